// Round 5
// baseline (527.545 us; speedup 1.0000x reference)
//
#include <hip/hip_runtime.h>

#define B_ 2
#define S_ 2048
#define E_ 1024
#define H_ 16
#define DH 64
#define MM (B_*S_)   // 4096
#define BHN (B_*H_)  // 32

typedef unsigned short u16;
typedef unsigned int u32;
typedef __attribute__((ext_vector_type(8))) __bf16 bf16x8;
typedef __attribute__((ext_vector_type(4))) float f32x4;
typedef __attribute__((ext_vector_type(8))) u16 u16x8;
typedef __attribute__((ext_vector_type(4))) u16 u16x4;

static __device__ __forceinline__ u16 f2bf(float f) {
  u32 u = __builtin_bit_cast(u32, f);
  u += 0x7fffu + ((u >> 16) & 1u);
  return (u16)(u >> 16);
}
static __device__ __forceinline__ float bf2f(u16 h) {
  return __builtin_bit_cast(float, (u32)h << 16);
}
// XOR swizzle for 128B-stride row-major LDS tiles (P slab; 0 conflicts measured).
static __device__ __forceinline__ u32 sw(u32 byte) {
  return byte ^ (((byte >> 7) & 7u) << 4);
}
static __device__ __forceinline__ bf16x8 frag(const u16* lds, u32 byte) {
  return *(const bf16x8*)((const char*)lds + byte);
}
static __device__ __forceinline__ bf16x8 gfrag(const u16* g) {
  return *(const bf16x8*)g;
}
static __device__ __forceinline__ f32x4 mfma16(bf16x8 a, bf16x8 b, f32x4 c) {
  return __builtin_amdgcn_mfma_f32_16x16x32_bf16(a, b, c, 0, 0, 0);
}
static __device__ __forceinline__ void gload_lds16(const u16* g, u16* lds_base) {
  __builtin_amdgcn_global_load_lds(
      (const __attribute__((address_space(1))) u32*)g,
      (__attribute__((address_space(3))) u32*)lds_base, 16, 0, 0);
}

#define L2E 1.44269504088896340736f

// ---------------- split: f32 -> (hi, lo) bf16 ----------------
struct SplitArg { const float* s; u16* h; u16* l; int n4; };

__global__ void split6_kernel(SplitArg a0, SplitArg a1, SplitArg a2,
                              SplitArg a3, SplitArg a4, SplitArg a5) {
  SplitArg A = (blockIdx.z == 0) ? a0 : (blockIdx.z == 1) ? a1 : (blockIdx.z == 2) ? a2
             : (blockIdx.z == 3) ? a3 : (blockIdx.z == 4) ? a4 : a5;
  int i = blockIdx.x * blockDim.x + threadIdx.x;
  int stride = gridDim.x * blockDim.x;
  if (A.l) {
    for (; i < A.n4; i += stride) {
      float4 v = ((const float4*)A.s)[i];
      u16x4 h, l;
      h.x = f2bf(v.x); l.x = f2bf(v.x - bf2f(h.x));
      h.y = f2bf(v.y); l.y = f2bf(v.y - bf2f(h.y));
      h.z = f2bf(v.z); l.z = f2bf(v.z - bf2f(h.z));
      h.w = f2bf(v.w); l.w = f2bf(v.w - bf2f(h.w));
      ((u16x4*)A.h)[i] = h;
      ((u16x4*)A.l)[i] = l;
    }
  } else {  // hi-only (value: lo is never consumed)
    for (; i < A.n4; i += stride) {
      float4 v = ((const float4*)A.s)[i];
      u16x4 h;
      h.x = f2bf(v.x); h.y = f2bf(v.y); h.z = f2bf(v.z); h.w = f2bf(v.w);
      ((u16x4*)A.h)[i] = h;
    }
  }
}

// ---------------- amask -> bitmask (128 u32) ----------------
__global__ void pack_mask(const int* __restrict__ am, u32* __restrict__ pm) {
  int w = threadIdx.x;            // 0..127: [b][word]
  if (w < 128) {
    int base = (w >> 6) * 2048 + (w & 63) * 32;
    u32 bits = 0;
#pragma unroll
    for (int j = 0; j < 8; ++j) {
      int4 v = *(const int4*)(am + base + j * 4);
      bits |= (v.x ? 1u : 0u) << (4 * j) | (v.y ? 1u : 0u) << (4 * j + 1) |
              (v.z ? 1u : 0u) << (4 * j + 2) | (v.w ? 1u : 0u) << (4 * j + 3);
    }
    pm[w] = bits;
  }
}

// ---------------- projection GEMM (m97 structure, UNCHANGED from R4) ----------------
struct ProjArgs {
  const u16* xhi; const u16* xlo; const u16* whi; const u16* wlo;
  const float* bias; u16* ohi; u16* olo; int mode;
};

__global__ __launch_bounds__(256, 3) void proj_gemm(ProjArgs a0, ProjArgs a1, ProjArgs a2) {
  ProjArgs A = (blockIdx.z == 0) ? a0 : (blockIdx.z == 1) ? a1 : a2;
  __shared__ u16 As[128 * 64];
  __shared__ u16 Bs[128 * 64];
  const int t = threadIdx.x;
  const int l = t & 63, wid = t >> 6;
  const int g = l >> 4, ln = l & 15;
  const int wm = wid >> 1, wn = wid & 1;
  int bid = blockIdx.y * 8 + blockIdx.x;
  int sid = (bid & 7) * 32 + (bid >> 3);     // XCD swizzle (256 % 8 == 0)
  const int m0 = (sid >> 3) * 128, e0 = (sid & 7) * 128;

  f32x4 acc[4][4] = {};
  const int nkt = (A.mode == 2) ? 32 : 48;

  for (int kt = 0; kt < nkt; ++kt) {
    int kp = kt * 64;
    const u16* asrc = (kp < 2048) ? A.xhi : A.xlo;
    const u16* bsrc = (kp < 1024 || kp >= 2048) ? A.whi : A.wlo;
    int kc = kp & 1023;
#pragma unroll
    for (int r = 0; r < 4; ++r) {
      int cr = wid * 4 + r;
      int row = cr * 8 + (l >> 3);
      int col = (l & 7) * 8;
      gload_lds16(asrc + (size_t)(m0 + row) * 1024 + kc + col, As + cr * 512);
      gload_lds16(bsrc + (size_t)(e0 + row) * 1024 + kc + col, Bs + cr * 512);
    }
    __syncthreads();
#pragma unroll
    for (int ks = 0; ks < 2; ++ks) {
      bf16x8 af[4], bfv[4];
#pragma unroll
      for (int i = 0; i < 4; ++i) {
        af[i] = frag(As, (u32)(wm * 64 + i * 16 + ln) * 128 + ks * 64 + g * 16);
        bfv[i] = frag(Bs, (u32)(wn * 64 + i * 16 + ln) * 128 + ks * 64 + g * 16);
      }
#pragma unroll
      for (int i = 0; i < 4; ++i)
#pragma unroll
        for (int j = 0; j < 4; ++j)
          acc[i][j] = mfma16(af[i], bfv[j], acc[i][j]);
    }
    __syncthreads();
  }

#pragma unroll
  for (int i = 0; i < 4; ++i) {
#pragma unroll
    for (int j = 0; j < 4; ++j) {
      int e = e0 + wn * 64 + j * 16 + ln;
      int h = e >> 6, d = e & 63;
      float bias = A.bias[e];
      if (A.mode < 2) {
#pragma unroll
        for (int r = 0; r < 4; ++r) {
          int m = m0 + wm * 64 + i * 16 + g * 4 + r;
          float v = acc[i][j][r] + bias;
          if (A.mode == 0) v *= L2E;       // fold log2(e): attn uses exp2
          int b = m >> 11, s = m & 2047;
          size_t idx = ((size_t)((b * 16 + h) * 2048 + s)) * 64 + d;
          u16 hv = f2bf(v);
          A.ohi[idx] = hv;
          A.olo[idx] = f2bf(v - bf2f(hv));
        }
      } else {
        int m = m0 + wm * 64 + i * 16 + g * 4;
        int b = m >> 11, s = m & 2047;
        u16x4 pv;
#pragma unroll
        for (int r = 0; r < 4; ++r) pv[r] = f2bf(acc[i][j][r] + bias);
        size_t idx = ((size_t)((b * 16 + h) * 64 + d)) * 2048 + s;
        *(u16x4*)(A.ohi + idx) = pv;
      }
    }
  }
}

// ---------------- attention: ZERO-BARRIER k-loop ----------------
// K hi/lo and V^T fragments loaded directly from global (L1/L2-resident;
// 4 bh per XCD via swizzle). LDS holds only the per-wave-private P slab.
// Waves are fully independent -> no __syncthreads in the main loop.
__global__ __launch_bounds__(256, 3) void attn_kernel(
    const u16* __restrict__ qhi, const u16* __restrict__ qlo,
    const u16* __restrict__ khi, const u16* __restrict__ klo,
    const u16* __restrict__ vt, const u32* __restrict__ pm,
    const float* __restrict__ dmask, float* __restrict__ out) {
  __shared__ u16 Ps[4 * 16 * 64];   // per-wave [16 q][64 k]

  const int t = threadIdx.x, l = t & 63, wid = t >> 6;
  const int g = l >> 4, ln = l & 15;

  int bid = blockIdx.y * 32 + blockIdx.x;
  int sid = (bid & 7) * 128 + (bid >> 3);   // XCD swizzle: 4 bh per XCD
  const int qt = sid & 31, bh = sid >> 5, b = bh >> 4;
  const int q0 = qt * 64;
  const int qrow = q0 + wid * 16 + ln;
  const size_t qg = ((size_t)bh * 2048 + qrow) * 64;
  const u32* pmb = pm + b * 64;

  bf16x8 qh[2], ql[2];
#pragma unroll
  for (int ks = 0; ks < 2; ++ks) {
    qh[ks] = *(const bf16x8*)(qhi + qg + ks * 32 + g * 8);
    ql[ks] = *(const bf16x8*)(qlo + qg + ks * 32 + g * 8);
  }

  const size_t dmrow = ((size_t)bh * 2048 + qrow) * 2048;
  float4 dmc[4], dmn[4];
  auto load_dm = [&](int kt, float4* d) {
    const int k0 = kt * 64;
#pragma unroll
    for (int i = 0; i < 4; ++i)
      d[i] = *(const float4*)(dmask + dmrow + k0 + i * 16 + 4 * g);
  };

  load_dm(0, dmc);

  f32x4 O[4] = {};
  float Zacc = 0.f;
  const u32 psbase = (u32)(wid * 2048 + ln * 128);
  // per-thread fragment offsets within a k-tile
  const u32 kfo = (u32)(ln * 64 + g * 8);          // + i*1024 + ks*32
  const size_t vbase0 = ((size_t)bh * 64 + ln) * 2048 + g * 8;  // + id*16*2048 + ks*32

  for (int kt = 0; kt < 32; ++kt) {
    const size_t kbase = ((size_t)bh * 2048 + kt * 64) * 64;
    // prefetch next dmask tile (the HBM stream) a full iteration ahead
    if (kt < 31) load_dm(kt + 1, dmn);
    u32 m0 = pmb[2 * kt], m1 = pmb[2 * kt + 1];   // uniform -> s_load

    // QK^T (3-term split): A = K rows direct from global, B = Q (regs).
    f32x4 sc[4] = {};
#pragma unroll
    for (int ks = 0; ks < 2; ++ks) {
#pragma unroll
      for (int i = 0; i < 4; ++i) {
        const size_t off = kbase + kfo + i * 1024 + ks * 32;
        bf16x8 akh = gfrag(khi + off);
        bf16x8 akl = gfrag(klo + off);
        sc[i] = mfma16(akh, qh[ks], sc[i]);
        sc[i] = mfma16(akh, ql[ks], sc[i]);
        sc[i] = mfma16(akl, qh[ks], sc[i]);
      }
    }

    // pad bits -> exp2 -> Z -> dropout -> packed P^T write (own slab, no sync)
#pragma unroll
    for (int i = 0; i < 4; ++i) {
      u32 mm = (i < 2 ? m0 : m1) >> (((i & 1) << 4) + 4 * g);
      float e0 = (mm & 1u) ? exp2f(sc[i][0]) : 0.f;
      float e1 = (mm & 2u) ? exp2f(sc[i][1]) : 0.f;
      float e2 = (mm & 4u) ? exp2f(sc[i][2]) : 0.f;
      float e3 = (mm & 8u) ? exp2f(sc[i][3]) : 0.f;
      Zacc += (e0 + e1) + (e2 + e3);
      u16x4 p;
      p.x = f2bf(e0 * dmc[i].x);
      p.y = f2bf(e1 * dmc[i].y);
      p.z = f2bf(e2 * dmc[i].z);
      p.w = f2bf(e3 * dmc[i].w);
      *(u16x4*)((char*)Ps + sw(psbase + i * 32 + g * 8)) = p;
    }

    // PV: O^T = V^T . P^T. A = V^T rows direct from global, B = P (own slab).
#pragma unroll
    for (int ks = 0; ks < 2; ++ks) {
      bf16x8 bP = frag(Ps, sw(psbase + ks * 64 + g * 16));
#pragma unroll
      for (int id = 0; id < 4; ++id) {
        bf16x8 aV = gfrag(vt + vbase0 + (size_t)id * 32768 + kt * 64 + ks * 32);
        O[id] = mfma16(aV, bP, O[id]);
      }
    }

    if (kt < 31) {
#pragma unroll
      for (int i = 0; i < 4; ++i) dmc[i] = dmn[i];
    }
  }

  float z = Zacc;
  z += __shfl_xor(z, 16, 64);
  z += __shfl_xor(z, 32, 64);
  float rz = 1.f / z;

#pragma unroll
  for (int id = 0; id < 4; ++id) {
    float4 o;
    o.x = O[id][0] * rz; o.y = O[id][1] * rz;
    o.z = O[id][2] * rz; o.w = O[id][3] * rz;
    *(float4*)(out + qg + id * 16 + 4 * g) = o;
  }
}

// ---------------- host ----------------
extern "C" void kernel_launch(void* const* d_in, const int* in_sizes, int n_in,
                              void* d_out, int out_size, void* d_ws, size_t ws_size,
                              hipStream_t stream) {
  const float* query = (const float*)d_in[0];
  const float* keyt  = (const float*)d_in[1];
  const float* value = (const float*)d_in[2];
  const int*   amask = (const int*)d_in[3];
  const float* dmask = (const float*)d_in[4];
  const float* Wq = (const float*)d_in[5];
  const float* bq = (const float*)d_in[6];
  const float* Wk = (const float*)d_in[7];
  const float* bk = (const float*)d_in[8];
  const float* Wv = (const float*)d_in[9];
  const float* bv = (const float*)d_in[10];

  char* ws = (char*)d_ws;
  size_t off = 0;
  auto alloc = [&](size_t bytes) {
    char* p = ws + off;
    off += (bytes + 255) & ~(size_t)255;
    return p;
  };
  const size_t XB = (size_t)MM * E_ * sizeof(u16);   // 8 MB
  const size_t WB = (size_t)E_ * E_ * sizeof(u16);   // 2 MB

  u16 *xh[3], *xl[3], *wh[3], *wl[3];
  for (int i = 0; i < 3; ++i) { xh[i] = (u16*)alloc(XB); xl[i] = (u16*)alloc(XB); }
  for (int i = 0; i < 3; ++i) { wh[i] = (u16*)alloc(WB); wl[i] = (u16*)alloc(WB); }
  u16* q_hi = (u16*)alloc(XB);
  u16* q_lo = (u16*)alloc(XB);
  u16* k_hi = (u16*)alloc(XB);
  u16* k_lo = (u16*)alloc(XB);
  u16* v_t  = (u16*)alloc(XB);
  u32* pmask = (u32*)alloc(512);
  if (off > ws_size) return;

  SplitArg sa[6] = {
      {query, xh[0], xl[0], MM * E_ / 4}, {keyt, xh[1], xl[1], MM * E_ / 4},
      {value, xh[2], nullptr, MM * E_ / 4}, {Wq, wh[0], wl[0], E_ * E_ / 4},
      {Wk, wh[1], wl[1], E_ * E_ / 4},    {Wv, wh[2], wl[2], E_ * E_ / 4},
  };
  split6_kernel<<<dim3(512, 1, 6), 256, 0, stream>>>(sa[0], sa[1], sa[2], sa[3], sa[4], sa[5]);
  pack_mask<<<1, 128, 0, stream>>>(amask, pmask);

  ProjArgs pa[3] = {
      {xh[0], xl[0], wh[0], wl[0], bq, q_hi, q_lo, 0},
      {xh[1], xl[1], wh[1], wl[1], bk, k_hi, k_lo, 1},
      {xh[2], nullptr, wh[2], wl[2], bv, v_t, nullptr, 2},
  };
  proj_gemm<<<dim3(8, 32, 3), 256, 0, stream>>>(pa[0], pa[1], pa[2]);

  attn_kernel<<<dim3(32, 32), 256, 0, stream>>>(
      q_hi, q_lo, k_hi, k_lo, v_t, pmask, dmask, (float*)d_out);
}

// Round 6
// 287.194 us; speedup vs baseline: 1.8369x; 1.8369x over previous
//
#include <hip/hip_runtime.h>

#define B_ 2
#define S_ 2048
#define E_ 1024
#define H_ 16
#define DH 64
#define MM (B_*S_)   // 4096
#define BHN (B_*H_)  // 32

typedef unsigned short u16;
typedef unsigned int u32;
typedef __attribute__((ext_vector_type(8))) __bf16 bf16x8;
typedef __attribute__((ext_vector_type(4))) float f32x4;
typedef __attribute__((ext_vector_type(8))) u16 u16x8;
typedef __attribute__((ext_vector_type(4))) u16 u16x4;

static __device__ __forceinline__ u16 f2bf(float f) {
  u32 u = __builtin_bit_cast(u32, f);
  u += 0x7fffu + ((u >> 16) & 1u);
  return (u16)(u >> 16);
}
static __device__ __forceinline__ float bf2f(u16 h) {
  return __builtin_bit_cast(float, (u32)h << 16);
}
// XOR swizzle for 128B-stride row-major LDS tiles.
static __device__ __forceinline__ u32 sw(u32 byte) {
  return byte ^ (((byte >> 7) & 7u) << 4);
}
static __device__ __forceinline__ bf16x8 frag(const u16* lds, u32 byte) {
  return *(const bf16x8*)((const char*)lds + byte);
}
static __device__ __forceinline__ f32x4 mfma16(bf16x8 a, bf16x8 b, f32x4 c) {
  return __builtin_amdgcn_mfma_f32_16x16x32_bf16(a, b, c, 0, 0, 0);
}
static __device__ __forceinline__ void gload_lds16(const u16* g, u16* lds_base) {
  __builtin_amdgcn_global_load_lds(
      (const __attribute__((address_space(1))) u32*)g,
      (__attribute__((address_space(3))) u32*)lds_base, 16, 0, 0);
}

#define L2E 1.44269504088896340736f

// ---------------- split: f32 -> (hi, lo) bf16 ----------------
struct SplitArg { const float* s; u16* h; u16* l; int n4; };

__global__ void split6_kernel(SplitArg a0, SplitArg a1, SplitArg a2,
                              SplitArg a3, SplitArg a4, SplitArg a5) {
  SplitArg A = (blockIdx.z == 0) ? a0 : (blockIdx.z == 1) ? a1 : (blockIdx.z == 2) ? a2
             : (blockIdx.z == 3) ? a3 : (blockIdx.z == 4) ? a4 : a5;
  int i = blockIdx.x * blockDim.x + threadIdx.x;
  int stride = gridDim.x * blockDim.x;
  if (A.l) {
    for (; i < A.n4; i += stride) {
      float4 v = ((const float4*)A.s)[i];
      u16x4 h, l;
      h.x = f2bf(v.x); l.x = f2bf(v.x - bf2f(h.x));
      h.y = f2bf(v.y); l.y = f2bf(v.y - bf2f(h.y));
      h.z = f2bf(v.z); l.z = f2bf(v.z - bf2f(h.z));
      h.w = f2bf(v.w); l.w = f2bf(v.w - bf2f(h.w));
      ((u16x4*)A.h)[i] = h;
      ((u16x4*)A.l)[i] = l;
    }
  } else {  // hi-only (value: lo is never consumed)
    for (; i < A.n4; i += stride) {
      float4 v = ((const float4*)A.s)[i];
      u16x4 h;
      h.x = f2bf(v.x); h.y = f2bf(v.y); h.z = f2bf(v.z); h.w = f2bf(v.w);
      ((u16x4*)A.h)[i] = h;
    }
  }
}

// ---------------- amask -> bitmask (128 u32) ----------------
__global__ void pack_mask(const int* __restrict__ am, u32* __restrict__ pm) {
  int w = threadIdx.x;            // 0..127: [b][word]
  if (w < 128) {
    int base = (w >> 6) * 2048 + (w & 63) * 32;
    u32 bits = 0;
#pragma unroll
    for (int j = 0; j < 8; ++j) {
      int4 v = *(const int4*)(am + base + j * 4);
      bits |= (v.x ? 1u : 0u) << (4 * j) | (v.y ? 1u : 0u) << (4 * j + 1) |
              (v.z ? 1u : 0u) << (4 * j + 2) | (v.w ? 1u : 0u) << (4 * j + 3);
    }
    pm[w] = bits;
  }
}

// ---------------- projection GEMM (m97 structure, UNCHANGED from R4) ----------------
struct ProjArgs {
  const u16* xhi; const u16* xlo; const u16* whi; const u16* wlo;
  const float* bias; u16* ohi; u16* olo; int mode;
};

__global__ __launch_bounds__(256, 3) void proj_gemm(ProjArgs a0, ProjArgs a1, ProjArgs a2) {
  ProjArgs A = (blockIdx.z == 0) ? a0 : (blockIdx.z == 1) ? a1 : a2;
  __shared__ u16 As[128 * 64];
  __shared__ u16 Bs[128 * 64];
  const int t = threadIdx.x;
  const int l = t & 63, wid = t >> 6;
  const int g = l >> 4, ln = l & 15;
  const int wm = wid >> 1, wn = wid & 1;
  int bid = blockIdx.y * 8 + blockIdx.x;
  int sid = (bid & 7) * 32 + (bid >> 3);     // XCD swizzle (256 % 8 == 0)
  const int m0 = (sid >> 3) * 128, e0 = (sid & 7) * 128;

  f32x4 acc[4][4] = {};
  const int nkt = (A.mode == 2) ? 32 : 48;

  for (int kt = 0; kt < nkt; ++kt) {
    int kp = kt * 64;
    const u16* asrc = (kp < 2048) ? A.xhi : A.xlo;
    const u16* bsrc = (kp < 1024 || kp >= 2048) ? A.whi : A.wlo;
    int kc = kp & 1023;
#pragma unroll
    for (int r = 0; r < 4; ++r) {
      int cr = wid * 4 + r;
      int row = cr * 8 + (l >> 3);
      int col = (l & 7) * 8;
      gload_lds16(asrc + (size_t)(m0 + row) * 1024 + kc + col, As + cr * 512);
      gload_lds16(bsrc + (size_t)(e0 + row) * 1024 + kc + col, Bs + cr * 512);
    }
    __syncthreads();
#pragma unroll
    for (int ks = 0; ks < 2; ++ks) {
      bf16x8 af[4], bfv[4];
#pragma unroll
      for (int i = 0; i < 4; ++i) {
        af[i] = frag(As, (u32)(wm * 64 + i * 16 + ln) * 128 + ks * 64 + g * 16);
        bfv[i] = frag(Bs, (u32)(wn * 64 + i * 16 + ln) * 128 + ks * 64 + g * 16);
      }
#pragma unroll
      for (int i = 0; i < 4; ++i)
#pragma unroll
        for (int j = 0; j < 4; ++j)
          acc[i][j] = mfma16(af[i], bfv[j], acc[i][j]);
    }
    __syncthreads();
  }

#pragma unroll
  for (int i = 0; i < 4; ++i) {
#pragma unroll
    for (int j = 0; j < 4; ++j) {
      int e = e0 + wn * 64 + j * 16 + ln;
      int h = e >> 6, d = e & 63;
      float bias = A.bias[e];
      if (A.mode < 2) {
#pragma unroll
        for (int r = 0; r < 4; ++r) {
          int m = m0 + wm * 64 + i * 16 + g * 4 + r;
          float v = acc[i][j][r] + bias;
          if (A.mode == 0) v *= L2E;       // fold log2(e): attn uses exp2
          int b = m >> 11, s = m & 2047;
          size_t idx = ((size_t)((b * 16 + h) * 2048 + s)) * 64 + d;
          u16 hv = f2bf(v);
          A.ohi[idx] = hv;
          A.olo[idx] = f2bf(v - bf2f(hv));
        }
      } else {
        int m = m0 + wm * 64 + i * 16 + g * 4;
        int b = m >> 11, s = m & 2047;
        u16x4 pv;
#pragma unroll
        for (int r = 0; r < 4; ++r) pv[r] = f2bf(acc[i][j][r] + bias);
        size_t idx = ((size_t)((b * 16 + h) * 64 + d)) * 2048 + s;
        *(u16x4*)(A.ohi + idx) = pv;
      }
    }
  }
}

// ---------------- attention: DMA-staged, double-buffered, 1 barrier/tile ----------------
// global_load_lds with linear LDS dest + inverse-swizzled global source (rule #21);
// reads keep the sw() swizzle. Next tile's DMA is in flight across the whole
// compute phase; single __syncthreads per tile drains it.
__global__ __launch_bounds__(256, 2) void attn_kernel(
    const u16* __restrict__ qhi, const u16* __restrict__ qlo,
    const u16* __restrict__ khi, const u16* __restrict__ klo,
    const u16* __restrict__ vt, const u32* __restrict__ pm,
    const float* __restrict__ dmask, float* __restrict__ out) {
  __shared__ u16 Ksh[2][64 * 64];
  __shared__ u16 Ksl[2][64 * 64];
  __shared__ u16 Vs[2][64 * 64];    // [d][k]
  __shared__ u16 Ps[4 * 16 * 64];   // per-wave [16 q][64 k]

  const int t = threadIdx.x, l = t & 63, wid = t >> 6;
  const int g = l >> 4, ln = l & 15;

  int bid = blockIdx.y * 32 + blockIdx.x;
  int sid = (bid & 7) * 128 + (bid >> 3);   // XCD swizzle: 4 bh per XCD
  const int qt = sid & 31, bh = sid >> 5, b = bh >> 4;
  const int q0 = qt * 64;
  const int qrow = q0 + wid * 16 + ln;
  const size_t qg = ((size_t)bh * 2048 + qrow) * 64;
  const u32* pmb = pm + b * 64;

  bf16x8 qh[2], ql[2];
#pragma unroll
  for (int ks = 0; ks < 2; ++ks) {
    qh[ks] = *(const bf16x8*)(qhi + qg + ks * 32 + g * 8);
    ql[ks] = *(const bf16x8*)(qlo + qg + ks * 32 + g * 8);
  }

  const size_t dmrow = ((size_t)bh * 2048 + qrow) * 2048;
  float4 dmc[4], dmn[4];
  auto load_dm = [&](int kt, float4* d) {
    const int k0 = kt * 64;
#pragma unroll
    for (int i = 0; i < 4; ++i)
      d[i] = *(const float4*)(dmask + dmrow + k0 + i * 16 + 4 * g);
  };

  // DMA-stage tile kt into buffer buf. Linear LDS dest (wave-uniform base +
  // lane*16); global source pre-permuted by the sw involution so that
  // swizzled reads see the right data.
  auto stage = [&](int buf, int kt) {
    const int k0 = kt * 64;
    const size_t kbase = ((size_t)bh * 2048 + k0) * 64;
    u16* khd = Ksh[buf];
    u16* kld = Ksl[buf];
    u16* vd = Vs[buf];
#pragma unroll
    for (int r = 0; r < 2; ++r) {
      int cbase = wid * 64 + 256 * r;        // wave-uniform chunk base
      int c = cbase + l;                     // this lane's dest chunk
      int c2 = c ^ ((c >> 3) & 7);           // source chunk (involution)
      gload_lds16(khi + kbase + c2 * 8, khd + cbase * 8);
      gload_lds16(klo + kbase + c2 * 8, kld + cbase * 8);
      gload_lds16(vt + ((size_t)bh * 64 + (c2 >> 3)) * 2048 + k0 + (c2 & 7) * 8,
                  vd + cbase * 8);
    }
  };

  load_dm(0, dmc);
  stage(0, 0);
  __syncthreads();

  f32x4 O[4] = {};
  float Zacc = 0.f;
  const u32 psbase = (u32)(wid * 2048 + ln * 128);

#pragma unroll 2
  for (int kt = 0; kt < 32; ++kt) {
    const int buf = kt & 1;
    // issue next tile's DMA + dmask prefetch; in flight across this compute
    if (kt < 31) {
      stage(buf ^ 1, kt + 1);
      load_dm(kt + 1, dmn);
    }
    u32 m0 = pmb[2 * kt], m1 = pmb[2 * kt + 1];   // uniform -> s_load

    // QK^T (3-term split): A = K rows (LDS), B = Q (regs).
    f32x4 sc[4] = {};
#pragma unroll
    for (int ks = 0; ks < 2; ++ks) {
#pragma unroll
      for (int i = 0; i < 4; ++i) {
        u32 byt = sw((u32)((i * 16 + ln) * 128 + ks * 64 + g * 16));
        bf16x8 akh = frag(Ksh[buf], byt);
        bf16x8 akl = frag(Ksl[buf], byt);
        sc[i] = mfma16(akh, qh[ks], sc[i]);
        sc[i] = mfma16(akh, ql[ks], sc[i]);
        sc[i] = mfma16(akl, qh[ks], sc[i]);
      }
    }

    // pad bits -> exp2 -> Z -> dropout -> packed P^T write (own slab, no sync)
#pragma unroll
    for (int i = 0; i < 4; ++i) {
      u32 mm = (i < 2 ? m0 : m1) >> (((i & 1) << 4) + 4 * g);
      float e0 = (mm & 1u) ? exp2f(sc[i][0]) : 0.f;
      float e1 = (mm & 2u) ? exp2f(sc[i][1]) : 0.f;
      float e2 = (mm & 4u) ? exp2f(sc[i][2]) : 0.f;
      float e3 = (mm & 8u) ? exp2f(sc[i][3]) : 0.f;
      Zacc += (e0 + e1) + (e2 + e3);
      u16x4 p;
      p.x = f2bf(e0 * dmc[i].x);
      p.y = f2bf(e1 * dmc[i].y);
      p.z = f2bf(e2 * dmc[i].z);
      p.w = f2bf(e3 * dmc[i].w);
      *(u16x4*)((char*)Ps + sw(psbase + i * 32 + g * 8)) = p;
    }

    // PV: O^T = V^T . P^T
#pragma unroll
    for (int ks = 0; ks < 2; ++ks) {
      bf16x8 bP = frag(Ps, sw(psbase + ks * 64 + g * 16));
#pragma unroll
      for (int id = 0; id < 4; ++id) {
        bf16x8 aV = frag(Vs[buf], sw((u32)((id * 16 + ln) * 128 + ks * 64 + g * 16)));
        O[id] = mfma16(aV, bP, O[id]);
      }
    }

    // single barrier: drains this wave's reads AND the block's DMA for buf^1
    __syncthreads();
    if (kt < 31) {
#pragma unroll
      for (int i = 0; i < 4; ++i) dmc[i] = dmn[i];
    }
  }

  float z = Zacc;
  z += __shfl_xor(z, 16, 64);
  z += __shfl_xor(z, 32, 64);
  float rz = 1.f / z;

#pragma unroll
  for (int id = 0; id < 4; ++id) {
    float4 o;
    o.x = O[id][0] * rz; o.y = O[id][1] * rz;
    o.z = O[id][2] * rz; o.w = O[id][3] * rz;
    *(float4*)(out + qg + id * 16 + 4 * g) = o;
  }
}

// ---------------- host ----------------
extern "C" void kernel_launch(void* const* d_in, const int* in_sizes, int n_in,
                              void* d_out, int out_size, void* d_ws, size_t ws_size,
                              hipStream_t stream) {
  const float* query = (const float*)d_in[0];
  const float* keyt  = (const float*)d_in[1];
  const float* value = (const float*)d_in[2];
  const int*   amask = (const int*)d_in[3];
  const float* dmask = (const float*)d_in[4];
  const float* Wq = (const float*)d_in[5];
  const float* bq = (const float*)d_in[6];
  const float* Wk = (const float*)d_in[7];
  const float* bk = (const float*)d_in[8];
  const float* Wv = (const float*)d_in[9];
  const float* bv = (const float*)d_in[10];

  char* ws = (char*)d_ws;
  size_t off = 0;
  auto alloc = [&](size_t bytes) {
    char* p = ws + off;
    off += (bytes + 255) & ~(size_t)255;
    return p;
  };
  const size_t XB = (size_t)MM * E_ * sizeof(u16);   // 8 MB
  const size_t WB = (size_t)E_ * E_ * sizeof(u16);   // 2 MB

  u16 *xh[3], *xl[3], *wh[3], *wl[3];
  for (int i = 0; i < 3; ++i) { xh[i] = (u16*)alloc(XB); xl[i] = (u16*)alloc(XB); }
  for (int i = 0; i < 3; ++i) { wh[i] = (u16*)alloc(WB); wl[i] = (u16*)alloc(WB); }
  u16* q_hi = (u16*)alloc(XB);
  u16* q_lo = (u16*)alloc(XB);
  u16* k_hi = (u16*)alloc(XB);
  u16* k_lo = (u16*)alloc(XB);
  u16* v_t  = (u16*)alloc(XB);
  u32* pmask = (u32*)alloc(512);
  if (off > ws_size) return;

  SplitArg sa[6] = {
      {query, xh[0], xl[0], MM * E_ / 4}, {keyt, xh[1], xl[1], MM * E_ / 4},
      {value, xh[2], nullptr, MM * E_ / 4}, {Wq, wh[0], wl[0], E_ * E_ / 4},
      {Wk, wh[1], wl[1], E_ * E_ / 4},    {Wv, wh[2], wl[2], E_ * E_ / 4},
  };
  split6_kernel<<<dim3(512, 1, 6), 256, 0, stream>>>(sa[0], sa[1], sa[2], sa[3], sa[4], sa[5]);
  pack_mask<<<1, 128, 0, stream>>>(amask, pmask);

  ProjArgs pa[3] = {
      {xh[0], xl[0], wh[0], wl[0], bq, q_hi, q_lo, 0},
      {xh[1], xl[1], wh[1], wl[1], bk, k_hi, k_lo, 1},
      {xh[2], nullptr, wh[2], wl[2], bv, v_t, nullptr, 2},
  };
  proj_gemm<<<dim3(8, 32, 3), 256, 0, stream>>>(pa[0], pa[1], pa[2]);

  attn_kernel<<<dim3(32, 32), 256, 0, stream>>>(
      q_hi, q_lo, k_hi, k_lo, v_t, pmask, dmask, (float*)d_out);
}